// Round 5
// baseline (273.815 us; speedup 1.0000x reference)
//
#include <hip/hip_runtime.h>
#include <hip/hip_bf16.h>
#include <stdint.h>

// MultiHeadAttention: B=2, L=2048, D=1024, H=16, F=64
// cvt -> GEMM qkv (dbuf stage-ahead, swizzled LDS; q*0.125*log2e, k, V^T via LDS transpose)
// -> flash attention (32x32x16 MFMA, in-register P via permlane32_swap, fixed-m exp2)
// -> GEMM proj (fp32 out)

typedef unsigned short u16;
typedef __attribute__((ext_vector_type(8))) short short8;
typedef __attribute__((ext_vector_type(4))) float f32x4;
typedef __attribute__((ext_vector_type(16))) float f32x16;
typedef __attribute__((ext_vector_type(4))) unsigned int u32x4;

#define MFMA16(a, b, c) __builtin_amdgcn_mfma_f32_16x16x32_bf16((a), (b), (c), 0, 0, 0)
#define MFMA32(a, b, c) __builtin_amdgcn_mfma_f32_32x32x16_bf16((a), (b), (c), 0, 0, 0)

__device__ __forceinline__ u16 f2bf(float x) {
  union { float f; uint32_t u; } v; v.f = x;
  uint32_t r = v.u + 0x7FFFu + ((v.u >> 16) & 1u);
  return (u16)(r >> 16);
}

__device__ __forceinline__ float fexp2(float x) {
#if __has_builtin(__builtin_amdgcn_exp2f)
  return __builtin_amdgcn_exp2f(x);
#else
  return exp2f(x);
#endif
}

// pack two f32 -> two bf16 (round half-up) in one u32
__device__ __forceinline__ uint32_t pkbf(float lo, float hi) {
  uint32_t a = __builtin_bit_cast(uint32_t, lo) + 0x8000u;
  uint32_t b = __builtin_bit_cast(uint32_t, hi) + 0x8000u;
  return __builtin_amdgcn_perm(b, a, 0x07060302u);
}

__device__ __forceinline__ void gload16(const void* g, void* l) {
  __builtin_amdgcn_global_load_lds((const __attribute__((address_space(1))) void*)g,
                                   (__attribute__((address_space(3))) void*)l, 16, 0, 0);
}

// ---------------- fp32 -> bf16 convert (merged) ----------------
__global__ __launch_bounds__(256) void cvt_all(const float* __restrict__ x,
                                               const float* __restrict__ wq,
                                               const float* __restrict__ wp,
                                               u16* __restrict__ xb,
                                               u16* __restrict__ wqb,
                                               u16* __restrict__ wpb) {
  int i = blockIdx.x * 256 + threadIdx.x;
  const float* s; u16* d; int off;
  if (i < 1048576) { s = x; d = xb; off = i; }
  else if (i < 1835008) { s = wq; d = wqb; off = i - 1048576; }
  else { s = wp; d = wpb; off = i - 1835008; }
  float4 f = reinterpret_cast<const float4*>(s)[off];
  ushort4 o;
  o.x = f2bf(f.x); o.y = f2bf(f.y); o.z = f2bf(f.z); o.w = f2bf(f.w);
  reinterpret_cast<ushort4*>(d)[off] = o;
}

// ---------------- bf16 GEMM: C = A B^T + bias ----------------
// 128x128 tile, BK=32, double-buffered LDS (stage-ahead), slot-swizzled.
// LDS 32KB: smem[2][A 4096 | B 4096] u16; epilogue reuses as sC[128*128].
// EPI 0: bn<8 -> q (scaled), bn<16 -> k, bn>=16 -> V^T via LDS transpose.
// EPI 1: fp32 row-major out.
template <int EPI>
__global__ __launch_bounds__(256, 5) void gemm_bt(const u16* __restrict__ A,
                                                  const u16* __restrict__ B,
                                                  const float* __restrict__ bias,
                                                  u16* __restrict__ outb,
                                                  float* __restrict__ outf,
                                                  int M, int N, int K) {
  __shared__ u16 smem[16384];  // 32 KB
  const int tid = threadIdx.x;
  const int lane = tid & 63;
  const int wid = tid >> 6;
  const int bn = blockIdx.x, bm = blockIdx.y;
  const int row0 = bm * 128, col0 = bn * 128;
  const int wr = wid >> 1, wc = wid & 1;
  const int fr = lane & 15, fq = lane >> 4;

  f32x4 acc[4][4];
  #pragma unroll
  for (int m = 0; m < 4; m++)
    #pragma unroll
    for (int n = 0; n < 4; n++)
      #pragma unroll
      for (int j = 0; j < 4; j++) acc[m][n][j] = 0.f;

  // staging geometry: 512 chunks of 8 u16 per 128x32 tile; chunk c -> row c>>2,
  // phys slot c&3 holds logical slot (c&3)^((c>>3)&3)  [source pre-swizzle]
  const int cB = tid + 256;
  const int rA1 = tid >> 2, rA2 = cB >> 2;
  const int lA1 = (tid & 3) ^ ((tid >> 3) & 3);
  const int lA2 = (cB & 3) ^ ((cB >> 3) & 3);
  const size_t ga1 = (size_t)rA1 * K + lA1 * 8;
  const size_t ga2 = (size_t)rA2 * K + lA2 * 8;
  const int d1 = tid * 8, d2 = cB * 8;
  const u16* Ab = A + (size_t)row0 * K;
  const u16* Bb = B + (size_t)col0 * K;

  // read-side swizzle: logical slot fq -> phys fq ^ ((row>>1)&3); row%16==fr
  const int sl = (fq ^ ((fr >> 1) & 3)) * 8;

  const int niter = K >> 5;

  // prologue: stage tile 0 into buf 0
  {
    u16* s = smem;
    gload16(Ab + ga1, s + d1);
    gload16(Ab + ga2, s + d2);
    gload16(Bb + ga1, s + 4096 + d1);
    gload16(Bb + ga2, s + 4096 + d2);
  }
  __syncthreads();

  for (int t = 0; t < niter; t++) {
    if (t + 1 < niter) {  // stage-ahead: issue before compute
      u16* s = smem + ((t + 1) & 1) * 8192;
      const size_t k0 = (size_t)(t + 1) * 32;
      gload16(Ab + ga1 + k0, s + d1);
      gload16(Ab + ga2 + k0, s + d2);
      gload16(Bb + ga1 + k0, s + 4096 + d1);
      gload16(Bb + ga2 + k0, s + 4096 + d2);
    }
    const u16* sa = smem + (t & 1) * 8192;
    const u16* sb = sa + 4096;
    short8 a[4], b[4];
    #pragma unroll
    for (int m = 0; m < 4; m++)
      a[m] = *(const short8*)&sa[(wr * 64 + m * 16 + fr) * 32 + sl];
    #pragma unroll
    for (int n = 0; n < 4; n++)
      b[n] = *(const short8*)&sb[(wc * 64 + n * 16 + fr) * 32 + sl];
    __builtin_amdgcn_s_setprio(1);
    #pragma unroll
    for (int m = 0; m < 4; m++)
      #pragma unroll
      for (int n = 0; n < 4; n++)
        acc[m][n] = MFMA16(a[m], b[n], acc[m][n]);
    __builtin_amdgcn_s_setprio(0);
    __syncthreads();  // drains vmcnt (incl. next-tile stage) + barrier
  }

  if (EPI == 0) {
    if (bn < 16) {
      // q (bn<8) / k (bn<16): [bh][l][64] scatter
      #pragma unroll
      for (int m = 0; m < 4; m++) {
        #pragma unroll
        for (int n = 0; n < 4; n++) {
          #pragma unroll
          for (int j = 0; j < 4; j++) {
            int r = row0 + wr * 64 + m * 16 + fq * 4 + j;
            int c = col0 + wc * 64 + n * 16 + fr;
            float v = acc[m][n][j] + bias[c];
            int d = c & 1023, h = d >> 6, f = d & 63;
            int bb = r >> 11, ll = r & 2047;
            int bhh = bb * 16 + h;
            if (bn < 8) {
              outb[((size_t)bhh * 2048 + ll) * 64 + f] = f2bf(v * 0.18033688f);
            } else {
              outb[4194304u + ((size_t)bhh * 2048 + ll) * 64 + f] = f2bf(v);
            }
          }
        }
      }
    } else {
      // V^T: stage bf16 tile in LDS (swizzled), then coalesced [f][l] writes
      u16* sC = smem;
      #pragma unroll
      for (int m = 0; m < 4; m++) {
        #pragma unroll
        for (int n = 0; n < 4; n++) {
          int c_local = wc * 64 + n * 16 + fr;
          int r_base = wr * 64 + m * 16 + fq * 4;
          float bi = bias[col0 + c_local];
          uint2 w;
          w.x = pkbf(acc[m][n][0] + bi, acc[m][n][1] + bi);
          w.y = pkbf(acc[m][n][2] + bi, acc[m][n][3] + bi);
          *(uint2*)&sC[c_local * 128 + (r_base ^ ((c_local & 7) << 3))] = w;
        }
      }
      __syncthreads();
      const int h0 = (col0 - 2048) >> 6;
      const int ll0 = row0 & 2047;
      const int bb = row0 >> 11;
      #pragma unroll
      for (int it = 0; it < 8; it++) {
        int chunk = tid + it * 256;
        int row_c = chunk >> 4, off = chunk & 15;
        short8 v = *(const short8*)&sC[row_c * 128 + ((off * 8) ^ ((row_c & 7) << 3))];
        int h = h0 + (row_c >> 6), f = row_c & 63;
        *(short8*)&outb[8388608u + ((size_t)((bb * 16 + h) * 64 + f)) * 2048 + ll0 + off * 8] = v;
      }
    }
  } else {
    #pragma unroll
    for (int m = 0; m < 4; m++)
      #pragma unroll
      for (int n = 0; n < 4; n++)
        #pragma unroll
        for (int j = 0; j < 4; j++) {
          int r = row0 + wr * 64 + m * 16 + fq * 4 + j;
          int c = col0 + wc * 64 + n * 16 + fr;
          outf[(size_t)r * N + c] = acc[m][n][j] + bias[c];
        }
  }
}

// ---------------- flash attention: 32x32x16 MFMA, in-register P ----------------
__device__ __forceinline__ void softpack(const f32x16& st, float& lp,
                                         short8& paA, short8& paB) {
  float e[16];
  #pragma unroll
  for (int r = 0; r < 16; r++) e[r] = fexp2(st[r]);
  #pragma unroll
  for (int r = 0; r < 16; r++) lp += e[r];
  #pragma unroll
  for (int cc = 0; cc < 2; cc++) {
    uint32_t g0 = pkbf(e[8 * cc + 0], e[8 * cc + 1]);
    uint32_t g1 = pkbf(e[8 * cc + 2], e[8 * cc + 3]);
    uint32_t g2 = pkbf(e[8 * cc + 4], e[8 * cc + 5]);
    uint32_t g3 = pkbf(e[8 * cc + 6], e[8 * cc + 7]);
    asm volatile("v_permlane32_swap_b32 %0, %1" : "+v"(g0), "+v"(g2));
    asm volatile("v_permlane32_swap_b32 %0, %1" : "+v"(g1), "+v"(g3));
    u32x4 t;
    t[0] = g0; t[1] = g1; t[2] = g2; t[3] = g3;
    if (cc == 0) paA = __builtin_bit_cast(short8, t);
    else paB = __builtin_bit_cast(short8, t);
  }
}

__global__ __launch_bounds__(128, 2) void attn_kernel(const u16* __restrict__ qg,
                                                      const u16* __restrict__ kg,
                                                      const u16* __restrict__ vtg,
                                                      u16* __restrict__ y) {
  __shared__ u16 sK[2][4096];
  __shared__ u16 sVt[2][4096];
  __shared__ float sLv[2][32];
  const int x = blockIdx.x;
  const int bh = (x & 7) * 4 + (x >> 8);   // 4 bh per XCD -> K/V L2-resident
  const int qt = (x >> 3) & 31;
  const int tid = threadIdx.x, l = tid & 63, wid = tid >> 6;
  const int col = l & 31, hi = l >> 5;
  const size_t base = (size_t)bh * 131072;
  const u16* qp = qg + base;
  const u16* kp = kg + base;
  const u16* vp = vtg + base;
  const int qrow = qt * 64 + wid * 32;

  short8 qf[4];
  #pragma unroll
  for (int kk = 0; kk < 4; kk++)
    qf[kk] = *(const short8*)&qp[(size_t)(qrow + col) * 64 + kk * 16 + hi * 8];

  int koff[4], voff[4], dst[4];
  #pragma unroll
  for (int j = 0; j < 4; j++) {
    int c = tid + j * 128;
    int row = c >> 3, slot = c & 7;
    int swc = (slot * 8) ^ ((row & 7) << 3);
    koff[j] = row * 64 + swc;
    voff[j] = row * 2048 + swc;
    dst[j] = c * 8;
  }

  f32x16 o0, o1;
  float lp = 0.f;
  #pragma unroll
  for (int r = 0; r < 16; r++) { o0[r] = 0.f; o1[r] = 0.f; }

  const int rsw = (col & 7) << 3;

  #pragma unroll
  for (int j = 0; j < 4; j++) {
    gload16(kp + koff[j], &sK[0][dst[j]]);
    gload16(vp + voff[j], &sVt[0][dst[j]]);
  }

  int sel = 0;
  for (int t0 = 0; t0 < 2048; t0 += 64) {
    __syncthreads();
    if (t0 + 64 < 2048) {
      const int tn = t0 + 64;
      #pragma unroll
      for (int j = 0; j < 4; j++) {
        gload16(kp + (size_t)tn * 64 + koff[j], &sK[sel ^ 1][dst[j]]);
        gload16(vp + tn + voff[j], &sVt[sel ^ 1][dst[j]]);
      }
    }
    const u16* Kt = sK[sel];
    const u16* Vt = sVt[sel];

    f32x16 st0, st1;
    #pragma unroll
    for (int r = 0; r < 16; r++) { st0[r] = 0.f; st1[r] = 0.f; }
    __builtin_amdgcn_s_setprio(1);
    #pragma unroll
    for (int kk = 0; kk < 4; kk++) {
      short8 kb0 = *(const short8*)&Kt[(col) * 64 + ((kk * 16 + hi * 8) ^ rsw)];
      short8 kb1 = *(const short8*)&Kt[(32 + col) * 64 + ((kk * 16 + hi * 8) ^ rsw)];
      st0 = MFMA32(kb0, qf[kk], st0);
      st1 = MFMA32(kb1, qf[kk], st1);
    }
    __builtin_amdgcn_s_setprio(0);

    short8 pa[4];
    softpack(st0, lp, pa[0], pa[1]);
    softpack(st1, lp, pa[2], pa[3]);

    __builtin_amdgcn_s_setprio(1);
    #pragma unroll
    for (int c = 0; c < 4; c++) {
      short8 vb0 = *(const short8*)&Vt[(col) * 64 + ((c * 16 + hi * 8) ^ rsw)];
      short8 vb1 = *(const short8*)&Vt[(32 + col) * 64 + ((c * 16 + hi * 8) ^ rsw)];
      o0 = MFMA32(pa[c], vb0, o0);
      o1 = MFMA32(pa[c], vb1, o1);
    }
    __builtin_amdgcn_s_setprio(0);
    sel ^= 1;
  }

  float lsum = lp + __shfl_xor(lp, 32);
  float linv = 1.0f / lsum;
  if (l < 32) sLv[wid][col] = linv;
  const int b = bh >> 4, hh = bh & 15;
  #pragma unroll
  for (int fvt = 0; fvt < 2; fvt++) {
    #pragma unroll
    for (int r = 0; r < 16; r++) {
      int q = (r & 3) + 8 * (r >> 2) + 4 * hi;
      float li = sLv[wid][q];
      float v = (fvt == 0 ? o0[r] : o1[r]) * li;
      y[((size_t)(b * 2048 + qrow + q)) * 1024 + hh * 64 + fvt * 32 + col] = f2bf(v);
    }
  }
}

// ---------------- launcher ----------------
extern "C" void kernel_launch(void* const* d_in, const int* in_sizes, int n_in,
                              void* d_out, int out_size, void* d_ws, size_t ws_size,
                              hipStream_t stream) {
  const float* x = (const float*)d_in[0];
  const float* w_qkv = (const float*)d_in[1];
  const float* b_qkv = (const float*)d_in[2];
  const float* w_proj = (const float*)d_in[3];
  const float* b_proj = (const float*)d_in[4];
  float* out = (float*)d_out;

  u16* ws = (u16*)d_ws;
  u16* xb = ws;                       // 4,194,304
  u16* wq = xb + 4194304;             // 3,145,728
  u16* wp = wq + 3145728;             // 1,048,576
  u16* qb = wp + 1048576;             // q / k / vt: 3 * 4,194,304
  u16* kb = qb + 4194304;
  u16* vb = kb + 4194304;
  u16* yb = vb + 4194304;             // 4,194,304

  cvt_all<<<8192, 256, 0, stream>>>(x, w_qkv, w_proj, xb, wq, wp);

  gemm_bt<0><<<dim3(24, 32), 256, 0, stream>>>(xb, wq, b_qkv, qb, nullptr, 4096, 3072, 1024);

  attn_kernel<<<1024, 128, 0, stream>>>(qb, kb, vb, yb);

  gemm_bt<1><<<dim3(8, 32), 256, 0, stream>>>(yb, wp, b_proj, nullptr, out, 4096, 1024, 1024);
}

// Round 6
// 121.231 us; speedup vs baseline: 2.2586x; 2.2586x over previous
//
#include <hip/hip_runtime.h>
#include <hip/hip_bf16.h>
#include <stdint.h>

// MultiHeadAttention: B=2, L=2048, D=1024, H=16, F=64
// cvt -> GEMM qkv (dbuf stage-ahead, swizzled LDS; q*0.125*log2e, k, V^T via LDS transpose)
// -> flash attention (32x32x16 MFMA, in-register P via permlane32_swap, fixed-m exp2)
// -> GEMM proj (fp32 out)
// NOTE: launch_bounds min-waves must respect the 64/128/256 VGPR occupancy steps:
// (256,5) forced VGPR<=64 -> acc spill -> 518MB scratch writes (round 5). Use (256,4).

typedef unsigned short u16;
typedef __attribute__((ext_vector_type(8))) short short8;
typedef __attribute__((ext_vector_type(4))) float f32x4;
typedef __attribute__((ext_vector_type(16))) float f32x16;
typedef __attribute__((ext_vector_type(4))) unsigned int u32x4;

#define MFMA16(a, b, c) __builtin_amdgcn_mfma_f32_16x16x32_bf16((a), (b), (c), 0, 0, 0)
#define MFMA32(a, b, c) __builtin_amdgcn_mfma_f32_32x32x16_bf16((a), (b), (c), 0, 0, 0)

__device__ __forceinline__ u16 f2bf(float x) {
  union { float f; uint32_t u; } v; v.f = x;
  uint32_t r = v.u + 0x7FFFu + ((v.u >> 16) & 1u);
  return (u16)(r >> 16);
}

__device__ __forceinline__ float fexp2(float x) {
#if __has_builtin(__builtin_amdgcn_exp2f)
  return __builtin_amdgcn_exp2f(x);
#else
  return exp2f(x);
#endif
}

// pack two f32 -> two bf16 (round half-up) in one u32
__device__ __forceinline__ uint32_t pkbf(float lo, float hi) {
  uint32_t a = __builtin_bit_cast(uint32_t, lo) + 0x8000u;
  uint32_t b = __builtin_bit_cast(uint32_t, hi) + 0x8000u;
  return __builtin_amdgcn_perm(b, a, 0x07060302u);
}

__device__ __forceinline__ void gload16(const void* g, void* l) {
  __builtin_amdgcn_global_load_lds((const __attribute__((address_space(1))) void*)g,
                                   (__attribute__((address_space(3))) void*)l, 16, 0, 0);
}

// ---------------- fp32 -> bf16 convert (merged) ----------------
__global__ __launch_bounds__(256) void cvt_all(const float* __restrict__ x,
                                               const float* __restrict__ wq,
                                               const float* __restrict__ wp,
                                               u16* __restrict__ xb,
                                               u16* __restrict__ wqb,
                                               u16* __restrict__ wpb) {
  int i = blockIdx.x * 256 + threadIdx.x;
  const float* s; u16* d; int off;
  if (i < 1048576) { s = x; d = xb; off = i; }
  else if (i < 1835008) { s = wq; d = wqb; off = i - 1048576; }
  else { s = wp; d = wpb; off = i - 1835008; }
  float4 f = reinterpret_cast<const float4*>(s)[off];
  ushort4 o;
  o.x = f2bf(f.x); o.y = f2bf(f.y); o.z = f2bf(f.z); o.w = f2bf(f.w);
  reinterpret_cast<ushort4*>(d)[off] = o;
}

// ---------------- bf16 GEMM: C = A B^T + bias ----------------
// 128x128 tile, BK=32, double-buffered LDS (stage-ahead), slot-swizzled.
// LDS 32KB: smem[2][A 4096 | B 4096] u16; epilogue reuses as sC[128*128].
// EPI 0: bn<8 -> q (scaled), bn<16 -> k, bn>=16 -> V^T via LDS transpose.
// EPI 1: fp32 row-major out.
template <int EPI>
__global__ __launch_bounds__(256, 4) void gemm_bt(const u16* __restrict__ A,
                                                  const u16* __restrict__ B,
                                                  const float* __restrict__ bias,
                                                  u16* __restrict__ outb,
                                                  float* __restrict__ outf,
                                                  int M, int N, int K) {
  __shared__ u16 smem[16384];  // 32 KB
  const int tid = threadIdx.x;
  const int lane = tid & 63;
  const int wid = tid >> 6;
  const int bn = blockIdx.x, bm = blockIdx.y;
  const int row0 = bm * 128, col0 = bn * 128;
  const int wr = wid >> 1, wc = wid & 1;
  const int fr = lane & 15, fq = lane >> 4;

  f32x4 acc[4][4];
  #pragma unroll
  for (int m = 0; m < 4; m++)
    #pragma unroll
    for (int n = 0; n < 4; n++)
      #pragma unroll
      for (int j = 0; j < 4; j++) acc[m][n][j] = 0.f;

  // staging geometry: 512 chunks of 8 u16 per 128x32 tile; chunk c -> row c>>2,
  // phys slot c&3 holds logical slot (c&3)^((c>>3)&3)  [source pre-swizzle]
  const int cB = tid + 256;
  const int rA1 = tid >> 2, rA2 = cB >> 2;
  const int lA1 = (tid & 3) ^ ((tid >> 3) & 3);
  const int lA2 = (cB & 3) ^ ((cB >> 3) & 3);
  const size_t ga1 = (size_t)rA1 * K + lA1 * 8;
  const size_t ga2 = (size_t)rA2 * K + lA2 * 8;
  const int d1 = tid * 8, d2 = cB * 8;
  const u16* Ab = A + (size_t)row0 * K;
  const u16* Bb = B + (size_t)col0 * K;

  // read-side swizzle: logical slot fq -> phys fq ^ ((row>>1)&3); row%16==fr
  const int sl = (fq ^ ((fr >> 1) & 3)) * 8;

  const int niter = K >> 5;

  // prologue: stage tile 0 into buf 0
  {
    u16* s = smem;
    gload16(Ab + ga1, s + d1);
    gload16(Ab + ga2, s + d2);
    gload16(Bb + ga1, s + 4096 + d1);
    gload16(Bb + ga2, s + 4096 + d2);
  }
  __syncthreads();

  for (int t = 0; t < niter; t++) {
    if (t + 1 < niter) {  // stage-ahead: issue before compute
      u16* s = smem + ((t + 1) & 1) * 8192;
      const size_t k0 = (size_t)(t + 1) * 32;
      gload16(Ab + ga1 + k0, s + d1);
      gload16(Ab + ga2 + k0, s + d2);
      gload16(Bb + ga1 + k0, s + 4096 + d1);
      gload16(Bb + ga2 + k0, s + 4096 + d2);
    }
    const u16* sa = smem + (t & 1) * 8192;
    const u16* sb = sa + 4096;
    short8 a[4], b[4];
    #pragma unroll
    for (int m = 0; m < 4; m++)
      a[m] = *(const short8*)&sa[(wr * 64 + m * 16 + fr) * 32 + sl];
    #pragma unroll
    for (int n = 0; n < 4; n++)
      b[n] = *(const short8*)&sb[(wc * 64 + n * 16 + fr) * 32 + sl];
    __builtin_amdgcn_s_setprio(1);
    #pragma unroll
    for (int m = 0; m < 4; m++)
      #pragma unroll
      for (int n = 0; n < 4; n++)
        acc[m][n] = MFMA16(a[m], b[n], acc[m][n]);
    __builtin_amdgcn_s_setprio(0);
    __syncthreads();  // drains vmcnt (incl. next-tile stage) + barrier
  }

  if (EPI == 0) {
    if (bn < 16) {
      // q (bn<8) / k (bn<16): [bh][l][64] scatter
      #pragma unroll
      for (int m = 0; m < 4; m++) {
        #pragma unroll
        for (int n = 0; n < 4; n++) {
          #pragma unroll
          for (int j = 0; j < 4; j++) {
            int r = row0 + wr * 64 + m * 16 + fq * 4 + j;
            int c = col0 + wc * 64 + n * 16 + fr;
            float v = acc[m][n][j] + bias[c];
            int d = c & 1023, h = d >> 6, f = d & 63;
            int bb = r >> 11, ll = r & 2047;
            int bhh = bb * 16 + h;
            if (bn < 8) {
              outb[((size_t)bhh * 2048 + ll) * 64 + f] = f2bf(v * 0.18033688f);
            } else {
              outb[4194304u + ((size_t)bhh * 2048 + ll) * 64 + f] = f2bf(v);
            }
          }
        }
      }
    } else {
      // V^T: stage bf16 tile in LDS (swizzled), then coalesced [f][l] writes
      u16* sC = smem;
      #pragma unroll
      for (int m = 0; m < 4; m++) {
        #pragma unroll
        for (int n = 0; n < 4; n++) {
          int c_local = wc * 64 + n * 16 + fr;
          int r_base = wr * 64 + m * 16 + fq * 4;
          float bi = bias[col0 + c_local];
          uint2 w;
          w.x = pkbf(acc[m][n][0] + bi, acc[m][n][1] + bi);
          w.y = pkbf(acc[m][n][2] + bi, acc[m][n][3] + bi);
          *(uint2*)&sC[c_local * 128 + (r_base ^ ((c_local & 7) << 3))] = w;
        }
      }
      __syncthreads();
      const int h0 = (col0 - 2048) >> 6;
      const int ll0 = row0 & 2047;
      const int bb = row0 >> 11;
      #pragma unroll
      for (int it = 0; it < 8; it++) {
        int chunk = tid + it * 256;
        int row_c = chunk >> 4, off = chunk & 15;
        short8 v = *(const short8*)&sC[row_c * 128 + ((off * 8) ^ ((row_c & 7) << 3))];
        int h = h0 + (row_c >> 6), f = row_c & 63;
        *(short8*)&outb[8388608u + ((size_t)((bb * 16 + h) * 64 + f)) * 2048 + ll0 + off * 8] = v;
      }
    }
  } else {
    #pragma unroll
    for (int m = 0; m < 4; m++)
      #pragma unroll
      for (int n = 0; n < 4; n++)
        #pragma unroll
        for (int j = 0; j < 4; j++) {
          int r = row0 + wr * 64 + m * 16 + fq * 4 + j;
          int c = col0 + wc * 64 + n * 16 + fr;
          outf[(size_t)r * N + c] = acc[m][n][j] + bias[c];
        }
  }
}

// ---------------- flash attention: 32x32x16 MFMA, in-register P ----------------
__device__ __forceinline__ void softpack(const f32x16& st, float& lp,
                                         short8& paA, short8& paB) {
  float e[16];
  #pragma unroll
  for (int r = 0; r < 16; r++) e[r] = fexp2(st[r]);
  #pragma unroll
  for (int r = 0; r < 16; r++) lp += e[r];
  #pragma unroll
  for (int cc = 0; cc < 2; cc++) {
    uint32_t g0 = pkbf(e[8 * cc + 0], e[8 * cc + 1]);
    uint32_t g1 = pkbf(e[8 * cc + 2], e[8 * cc + 3]);
    uint32_t g2 = pkbf(e[8 * cc + 4], e[8 * cc + 5]);
    uint32_t g3 = pkbf(e[8 * cc + 6], e[8 * cc + 7]);
    asm volatile("v_permlane32_swap_b32 %0, %1" : "+v"(g0), "+v"(g2));
    asm volatile("v_permlane32_swap_b32 %0, %1" : "+v"(g1), "+v"(g3));
    u32x4 t;
    t[0] = g0; t[1] = g1; t[2] = g2; t[3] = g3;
    if (cc == 0) paA = __builtin_bit_cast(short8, t);
    else paB = __builtin_bit_cast(short8, t);
  }
}

__global__ __launch_bounds__(128, 2) void attn_kernel(const u16* __restrict__ qg,
                                                      const u16* __restrict__ kg,
                                                      const u16* __restrict__ vtg,
                                                      u16* __restrict__ y) {
  __shared__ u16 sK[2][4096];
  __shared__ u16 sVt[2][4096];
  __shared__ float sLv[2][32];
  const int x = blockIdx.x;
  const int bh = (x & 7) * 4 + (x >> 8);   // 4 bh per XCD -> K/V L2-resident
  const int qt = (x >> 3) & 31;
  const int tid = threadIdx.x, l = tid & 63, wid = tid >> 6;
  const int col = l & 31, hi = l >> 5;
  const size_t base = (size_t)bh * 131072;
  const u16* qp = qg + base;
  const u16* kp = kg + base;
  const u16* vp = vtg + base;
  const int qrow = qt * 64 + wid * 32;

  short8 qf[4];
  #pragma unroll
  for (int kk = 0; kk < 4; kk++)
    qf[kk] = *(const short8*)&qp[(size_t)(qrow + col) * 64 + kk * 16 + hi * 8];

  int koff[4], voff[4], dst[4];
  #pragma unroll
  for (int j = 0; j < 4; j++) {
    int c = tid + j * 128;
    int row = c >> 3, slot = c & 7;
    int swc = (slot * 8) ^ ((row & 7) << 3);
    koff[j] = row * 64 + swc;
    voff[j] = row * 2048 + swc;
    dst[j] = c * 8;
  }

  f32x16 o0, o1;
  float lp = 0.f;
  #pragma unroll
  for (int r = 0; r < 16; r++) { o0[r] = 0.f; o1[r] = 0.f; }

  const int rsw = (col & 7) << 3;

  #pragma unroll
  for (int j = 0; j < 4; j++) {
    gload16(kp + koff[j], &sK[0][dst[j]]);
    gload16(vp + voff[j], &sVt[0][dst[j]]);
  }

  int sel = 0;
  for (int t0 = 0; t0 < 2048; t0 += 64) {
    __syncthreads();
    if (t0 + 64 < 2048) {
      const int tn = t0 + 64;
      #pragma unroll
      for (int j = 0; j < 4; j++) {
        gload16(kp + (size_t)tn * 64 + koff[j], &sK[sel ^ 1][dst[j]]);
        gload16(vp + tn + voff[j], &sVt[sel ^ 1][dst[j]]);
      }
    }
    const u16* Kt = sK[sel];
    const u16* Vt = sVt[sel];

    f32x16 st0, st1;
    #pragma unroll
    for (int r = 0; r < 16; r++) { st0[r] = 0.f; st1[r] = 0.f; }
    __builtin_amdgcn_s_setprio(1);
    #pragma unroll
    for (int kk = 0; kk < 4; kk++) {
      short8 kb0 = *(const short8*)&Kt[(col) * 64 + ((kk * 16 + hi * 8) ^ rsw)];
      short8 kb1 = *(const short8*)&Kt[(32 + col) * 64 + ((kk * 16 + hi * 8) ^ rsw)];
      st0 = MFMA32(kb0, qf[kk], st0);
      st1 = MFMA32(kb1, qf[kk], st1);
    }
    __builtin_amdgcn_s_setprio(0);

    short8 pa[4];
    softpack(st0, lp, pa[0], pa[1]);
    softpack(st1, lp, pa[2], pa[3]);

    __builtin_amdgcn_s_setprio(1);
    #pragma unroll
    for (int c = 0; c < 4; c++) {
      short8 vb0 = *(const short8*)&Vt[(col) * 64 + ((c * 16 + hi * 8) ^ rsw)];
      short8 vb1 = *(const short8*)&Vt[(32 + col) * 64 + ((c * 16 + hi * 8) ^ rsw)];
      o0 = MFMA32(pa[c], vb0, o0);
      o1 = MFMA32(pa[c], vb1, o1);
    }
    __builtin_amdgcn_s_setprio(0);
    sel ^= 1;
  }

  float lsum = lp + __shfl_xor(lp, 32);
  float linv = 1.0f / lsum;
  if (l < 32) sLv[wid][col] = linv;
  const int b = bh >> 4, hh = bh & 15;
  #pragma unroll
  for (int fvt = 0; fvt < 2; fvt++) {
    #pragma unroll
    for (int r = 0; r < 16; r++) {
      int q = (r & 3) + 8 * (r >> 2) + 4 * hi;
      float li = sLv[wid][q];
      float v = (fvt == 0 ? o0[r] : o1[r]) * li;
      y[((size_t)(b * 2048 + qrow + q)) * 1024 + hh * 64 + fvt * 32 + col] = f2bf(v);
    }
  }
}

// ---------------- launcher ----------------
extern "C" void kernel_launch(void* const* d_in, const int* in_sizes, int n_in,
                              void* d_out, int out_size, void* d_ws, size_t ws_size,
                              hipStream_t stream) {
  const float* x = (const float*)d_in[0];
  const float* w_qkv = (const float*)d_in[1];
  const float* b_qkv = (const float*)d_in[2];
  const float* w_proj = (const float*)d_in[3];
  const float* b_proj = (const float*)d_in[4];
  float* out = (float*)d_out;

  u16* ws = (u16*)d_ws;
  u16* xb = ws;                       // 4,194,304
  u16* wq = xb + 4194304;             // 3,145,728
  u16* wp = wq + 3145728;             // 1,048,576
  u16* qb = wp + 1048576;             // q / k / vt: 3 * 4,194,304
  u16* kb = qb + 4194304;
  u16* vb = kb + 4194304;
  u16* yb = vb + 4194304;             // 4,194,304

  cvt_all<<<8192, 256, 0, stream>>>(x, w_qkv, w_proj, xb, wq, wp);

  gemm_bt<0><<<dim3(24, 32), 256, 0, stream>>>(xb, wq, b_qkv, qb, nullptr, 4096, 3072, 1024);

  attn_kernel<<<1024, 128, 0, stream>>>(qb, kb, vb, yb);

  gemm_bt<1><<<dim3(8, 32), 256, 0, stream>>>(yb, wp, b_proj, nullptr, out, 4096, 1024, 1024);
}